// Round 10
// baseline (594.264 us; speedup 1.0000x reference)
//
#include <hip/hip_runtime.h>

// Problem constants (from reference): T=512, N=1024, MC=512, H=5, M=20, NF=20
#define T_DIM 512
#define N_DIM 1024
#define MC_DIM 512
#define H_DIM 5
#define M_WIN 20
#define NF_DIM 20

typedef __attribute__((ext_vector_type(8))) short short8;
typedef __attribute__((ext_vector_type(4))) float f32x4;

__device__ __forceinline__ unsigned short f2bf(float f) {
  unsigned int u = __float_as_uint(f);
  u += 0x7fffu + ((u >> 16) & 1u);   // round-to-nearest-even
  return (unsigned short)(u >> 16);
}

// ---------------------------------------------------------------------------
// WW[t,i,n] = sum_k phi[k,i] * Wpad[t+k, n]  (bf16 out)   grid (N/256, T)
__global__ __launch_bounds__(256) void ww_kernel(const float* __restrict__ W,
                                                 const float* __restrict__ phi,
                                                 unsigned short* __restrict__ WWb) {
  __shared__ float phis[M_WIN * H_DIM];
  int tid = threadIdx.x;
  if (tid < M_WIN * H_DIM) phis[tid] = phi[tid];
  __syncthreads();
  int n = blockIdx.x * 256 + tid;
  int t = blockIdx.y;
  float acc[H_DIM] = {0.f, 0.f, 0.f, 0.f, 0.f};
  int k0 = 19 - t; if (k0 < 0) k0 = 0;
  for (int k = k0; k < M_WIN; ++k) {
    float wv = W[(t + k - 19) * N_DIM + n];
#pragma unroll
    for (int i = 0; i < H_DIM; ++i) acc[i] += phis[k * H_DIM + i] * wv;
  }
#pragma unroll
  for (int i = 0; i < H_DIM; ++i)
    WWb[(size_t)(t * H_DIM + i) * N_DIM + n] = f2bf(acc[i]);
}

// Esc[c,i,n] = sigma[i]^0.25 * E[c,n,i]   (bf16 out)   grid (N/256, MC)
__global__ __launch_bounds__(256) void esc_kernel(const float* __restrict__ E,
                                                  const float* __restrict__ sigma,
                                                  unsigned short* __restrict__ Escb) {
  int tid = threadIdx.x;
  int n = blockIdx.x * 256 + tid;
  int c = blockIdx.y;
#pragma unroll
  for (int i = 0; i < H_DIM; ++i) {
    float s4 = powf(sigma[i], 0.25f);
    float v = E[((size_t)c * N_DIM + n) * H_DIM + i] * s4;
    Escb[(size_t)(c * H_DIM + i) * N_DIM + n] = f2bf(v);
  }
}

// Et2[n][(f,c)] = E_stu[f,c,n]  fp32 (10240x1024) -> bf16 (1024x10240) transpose
__global__ __launch_bounds__(256) void transpose_conv_kernel(const float* __restrict__ in,
                                                             unsigned short* __restrict__ out) {
  __shared__ float tile[32][33];
  int tx = threadIdx.x & 31, ty = threadIdx.x >> 5;
  int d0 = blockIdx.x * 32, n0 = blockIdx.y * 32;
#pragma unroll
  for (int k = 0; k < 4; ++k) {
    int r = ty + k * 8;
    tile[r][tx] = in[(size_t)(d0 + r) * N_DIM + n0 + tx];
  }
  __syncthreads();
#pragma unroll
  for (int k = 0; k < 4; ++k) {
    int r = ty + k * 8;
    out[(size_t)(n0 + r) * 10240 + d0 + tx] = f2bf(tile[tx][r]);
  }
}

// ---------------------------------------------------------------------------
// Generic C(MxN) = A(MxD) * B(NxD)^T, bf16 MFMA, 128x128 tile, BK=32.
// Grid: x = K-split (fastest -> XCD locality), y = N-tile, z = M-tile.
// mode: 0 = fp32 store, 1 = atomicAdd, 3 = bf16 store (C cast to ushort*).
template <bool AF32, bool BF32>
__global__ __launch_bounds__(256) void gemm_bt(const void* __restrict__ Ap,
                                               const void* __restrict__ Bp,
                                               float* __restrict__ C,
                                               int Ddim, int Ncols, int kChunk, int mode) {
  __shared__ unsigned short As[128 * 32];
  __shared__ unsigned short Bs[128 * 32];
  int tid = threadIdx.x;
  int lane = tid & 63, wave = tid >> 6;
  int wr = (wave >> 1) * 64, wc = (wave & 1) * 64;
  int m0 = blockIdx.z * 128, n0 = blockIdx.y * 128;
  int kBeg = blockIdx.x * kChunk, kEnd = kBeg + kChunk;
  int srow = tid >> 1, scol = (tid & 1) * 16;
  f32x4 zero = {0.f, 0.f, 0.f, 0.f};
  f32x4 acc[4][4];
#pragma unroll
  for (int i = 0; i < 4; ++i)
#pragma unroll
    for (int j = 0; j < 4; ++j) acc[i][j] = zero;

  int fr = lane & 15, fq = lane >> 4;

  for (int kk = kBeg; kk < kEnd; kk += 32) {
    if (AF32) {
      const float* A = (const float*)Ap;
      const float4* src = (const float4*)(A + (size_t)(m0 + srow) * Ddim + kk + scol);
      float4 v0 = src[0], v1 = src[1], v2 = src[2], v3 = src[3];
      float vals[16] = {v0.x, v0.y, v0.z, v0.w, v1.x, v1.y, v1.z, v1.w,
                        v2.x, v2.y, v2.z, v2.w, v3.x, v3.y, v3.z, v3.w};
      unsigned int pk[8];
#pragma unroll
      for (int e = 0; e < 8; ++e)
        pk[e] = (unsigned int)f2bf(vals[2 * e]) | ((unsigned int)f2bf(vals[2 * e + 1]) << 16);
      uint4* dst = (uint4*)&As[srow * 32 + scol];
      dst[0] = make_uint4(pk[0], pk[1], pk[2], pk[3]);
      dst[1] = make_uint4(pk[4], pk[5], pk[6], pk[7]);
    } else {
      const unsigned short* A = (const unsigned short*)Ap;
      const uint4* src = (const uint4*)(A + (size_t)(m0 + srow) * Ddim + kk + scol);
      uint4* dst = (uint4*)&As[srow * 32 + scol];
      dst[0] = src[0];
      dst[1] = src[1];
    }
    if (BF32) {
      const float* B = (const float*)Bp;
      const float4* src = (const float4*)(B + (size_t)(n0 + srow) * Ddim + kk + scol);
      float4 v0 = src[0], v1 = src[1], v2 = src[2], v3 = src[3];
      float vals[16] = {v0.x, v0.y, v0.z, v0.w, v1.x, v1.y, v1.z, v1.w,
                        v2.x, v2.y, v2.z, v2.w, v3.x, v3.y, v3.z, v3.w};
      unsigned int pk[8];
#pragma unroll
      for (int e = 0; e < 8; ++e)
        pk[e] = (unsigned int)f2bf(vals[2 * e]) | ((unsigned int)f2bf(vals[2 * e + 1]) << 16);
      uint4* dst = (uint4*)&Bs[srow * 32 + scol];
      dst[0] = make_uint4(pk[0], pk[1], pk[2], pk[3]);
      dst[1] = make_uint4(pk[4], pk[5], pk[6], pk[7]);
    } else {
      const unsigned short* B = (const unsigned short*)Bp;
      const uint4* src = (const uint4*)(B + (size_t)(n0 + srow) * Ddim + kk + scol);
      uint4* dst = (uint4*)&Bs[srow * 32 + scol];
      dst[0] = src[0];
      dst[1] = src[1];
    }
    __syncthreads();
    short8 af[4], bf_[4];
#pragma unroll
    for (int i = 0; i < 4; ++i)
      af[i] = *(const short8*)&As[(wr + i * 16 + fr) * 32 + fq * 8];
#pragma unroll
    for (int j = 0; j < 4; ++j)
      bf_[j] = *(const short8*)&Bs[(wc + j * 16 + fr) * 32 + fq * 8];
#pragma unroll
    for (int i = 0; i < 4; ++i)
#pragma unroll
      for (int j = 0; j < 4; ++j)
        acc[i][j] = __builtin_amdgcn_mfma_f32_16x16x32_bf16(af[i], bf_[j], acc[i][j], 0, 0, 0);
    __syncthreads();
  }
#pragma unroll
  for (int i = 0; i < 4; ++i) {
#pragma unroll
    for (int j = 0; j < 4; ++j) {
      int mBase = m0 + wr + i * 16 + fq * 4;
      int nIdx = n0 + wc + j * 16 + fr;
#pragma unroll
      for (int r = 0; r < 4; ++r) {
        float v = acc[i][j][r];
        size_t oidx = (size_t)(mBase + r) * Ncols + nIdx;
        if (mode == 0) C[oidx] = v;
        else if (mode == 1) atomicAdd(&C[oidx], v);
        else ((unsigned short*)C)[oidx] = f2bf(v);
      }
    }
  }
}

// ---------------------------------------------------------------------------
// f-batched GEMM: out[t,n] += phi_stu[t,f] * (A(512xKA) * B_f(Ncols x 512)^T)
// A: bf16, row stride 512 (the current U iterate). B: bf16, row stride 10240,
// f-block at column offset f*512 (Cb or Et2 layout). Grid: x = f*KS + ks
// (fastest -> f spread across XCDs), y = N-tile, z = M-tile. kChunk = 512/KS.
template <int KS>
__global__ __launch_bounds__(256) void gemm_fbat(const unsigned short* __restrict__ A,
                                                 const unsigned short* __restrict__ B,
                                                 float* __restrict__ C,
                                                 int Ncols, const float* __restrict__ phistu) {
  __shared__ unsigned short As[128 * 32];
  __shared__ unsigned short Bs[128 * 32];
  const int kChunk = 512 / KS;
  int tid = threadIdx.x;
  int lane = tid & 63, wave = tid >> 6;
  int wr = (wave >> 1) * 64, wc = (wave & 1) * 64;
  int f = blockIdx.x / KS, ks = blockIdx.x % KS;
  int m0 = blockIdx.z * 128, n0 = blockIdx.y * 128;
  int kBeg = ks * kChunk, kEnd = kBeg + kChunk;
  int srow = tid >> 1, scol = (tid & 1) * 16;
  f32x4 zero = {0.f, 0.f, 0.f, 0.f};
  f32x4 acc[4][4];
#pragma unroll
  for (int i = 0; i < 4; ++i)
#pragma unroll
    for (int j = 0; j < 4; ++j) acc[i][j] = zero;

  int fr = lane & 15, fq = lane >> 4;

  for (int kk = kBeg; kk < kEnd; kk += 32) {
    {
      const uint4* src = (const uint4*)(A + (size_t)(m0 + srow) * 512 + kk + scol);
      uint4* dst = (uint4*)&As[srow * 32 + scol];
      dst[0] = src[0];
      dst[1] = src[1];
    }
    {
      const uint4* src = (const uint4*)(B + (size_t)(n0 + srow) * 10240 + f * 512 + kk + scol);
      uint4* dst = (uint4*)&Bs[srow * 32 + scol];
      dst[0] = src[0];
      dst[1] = src[1];
    }
    __syncthreads();
    short8 af[4], bf_[4];
#pragma unroll
    for (int i = 0; i < 4; ++i)
      af[i] = *(const short8*)&As[(wr + i * 16 + fr) * 32 + fq * 8];
#pragma unroll
    for (int j = 0; j < 4; ++j)
      bf_[j] = *(const short8*)&Bs[(wc + j * 16 + fr) * 32 + fq * 8];
#pragma unroll
    for (int i = 0; i < 4; ++i)
#pragma unroll
      for (int j = 0; j < 4; ++j)
        acc[i][j] = __builtin_amdgcn_mfma_f32_16x16x32_bf16(af[i], bf_[j], acc[i][j], 0, 0, 0);
    __syncthreads();
  }
#pragma unroll
  for (int i = 0; i < 4; ++i) {
#pragma unroll
    for (int j = 0; j < 4; ++j) {
      int mBase = m0 + wr + i * 16 + fq * 4;
      int nIdx = n0 + wc + j * 16 + fr;
#pragma unroll
      for (int r = 0; r < 4; ++r) {
        int t = mBase + r;
        float s = phistu[t * NF_DIM + f];
        atomicAdd(&C[(size_t)t * Ncols + nIdx], s * acc[i][j][r]);
      }
    }
  }
}

// ---------------------------------------------------------------------------
// P[t,c] = upert[t,c] + bias[c]; also emit bf16 copy (iteration-0 operand)
__global__ __launch_bounds__(256) void padd_kernel(const float* __restrict__ upert,
                                                   const float* __restrict__ bias,
                                                   float* __restrict__ P,
                                                   unsigned short* __restrict__ Ubf0) {
  int i = blockIdx.x * 256 + threadIdx.x;
  float v = upert[i] + bias[i & (MC_DIM - 1)];
  P[i] = v;
  Ubf0[i] = f2bf(v);
}

// Tot2[ch,c] = sum of B rows in chunk ch   grid (2, 16)
__global__ __launch_bounds__(256) void bsum_kernel(const float* __restrict__ B,
                                                   float* __restrict__ Tot2) {
  int c = blockIdx.x * 256 + threadIdx.x;
  int ch = blockIdx.y;
  float s = 0.f;
#pragma unroll 8
  for (int k = 0; k < 32; ++k) s += B[(size_t)(ch * 32 + k) * MC_DIM + c];
  Tot2[ch * MC_DIM + c] = s;
}

// U_next[t,c] = P[t,c] - (exclusive prefix of B over t)   grid (2, 16)
// Writes bf16 next iterate; on the last sweep also writes fp32 U.
__global__ __launch_bounds__(256) void bscan_kernel(const float* __restrict__ B,
                                                    const float* __restrict__ Tot2,
                                                    const float* __restrict__ P,
                                                    unsigned short* __restrict__ Ubf_next,
                                                    float* __restrict__ Ufin, int last) {
  int c = blockIdx.x * 256 + threadIdx.x;
  int ch = blockIdx.y;
  float acc = 0.f;
  for (int p = 0; p < ch; ++p) acc += Tot2[p * MC_DIM + c];
  int t0 = ch * 32;
#pragma unroll 8
  for (int k = 0; k < 32; ++k) {
    int t = t0 + k;
    size_t idx = (size_t)t * MC_DIM + c;
    float un = P[idx] - acc;
    Ubf_next[idx] = f2bf(un);
    if (last) Ufin[idx] = un;
    acc += B[idx];
  }
}

// ---- chunked exclusive prefix over t of G (T x N) -> X ----
__global__ __launch_bounds__(256) void scan1_kernel(const float* __restrict__ G, float* __restrict__ Psum) {
  int n = blockIdx.x * 256 + threadIdx.x;
  int c = blockIdx.y;
  float s = 0.f;
  for (int j = 0; j < 32; ++j) s += G[(size_t)(c * 32 + j) * N_DIM + n];
  Psum[c * N_DIM + n] = s;
}
__global__ __launch_bounds__(256) void scan2_kernel(float* __restrict__ Psum) {
  int n = blockIdx.x * 256 + threadIdx.x;
  float run = 0.f;
  for (int c = 0; c < 16; ++c) {
    float v = Psum[c * N_DIM + n];
    Psum[c * N_DIM + n] = run;
    run += v;
  }
}
__global__ __launch_bounds__(256) void scan3_kernel(const float* __restrict__ G, const float* __restrict__ Psum,
                                                    float* __restrict__ X) {
  int n = blockIdx.x * 256 + threadIdx.x;
  int c = blockIdx.y;
  float x = Psum[c * N_DIM + n];
  for (int j = 0; j < 32; ++j) {
    int t = c * 32 + j;
    X[(size_t)t * N_DIM + n] = x;
    x += G[(size_t)t * N_DIM + n];
  }
}

// losses[t] = dot(XQ[t], X[t]) + dot(UR[t], U[t])
__global__ __launch_bounds__(256) void loss_kernel(const float* __restrict__ XQ, const float* __restrict__ X,
                                                   const float* __restrict__ UR, const float* __restrict__ U,
                                                   float* __restrict__ out) {
  int t = blockIdx.x, tid = threadIdx.x;
  float s = 0.f;
  for (int j = tid; j < N_DIM; j += 256) s += XQ[(size_t)t * N_DIM + j] * X[(size_t)t * N_DIM + j];
  for (int c = tid; c < MC_DIM; c += 256) s += UR[(size_t)t * MC_DIM + c] * U[(size_t)t * MC_DIM + c];
#pragma unroll
  for (int off = 32; off > 0; off >>= 1) s += __shfl_down(s, off);
  __shared__ float red[4];
  if ((tid & 63) == 0) red[tid >> 6] = s;
  __syncthreads();
  if (tid == 0) out[t] = red[0] + red[1] + red[2] + red[3];
}

// ---------------------------------------------------------------------------
extern "C" void kernel_launch(void* const* d_in, const int* in_sizes, int n_in,
                              void* d_out, int out_size, void* d_ws, size_t ws_size,
                              hipStream_t stream) {
  const float* Q      = (const float*)d_in[0];
  const float* R      = (const float*)d_in[1];
  const float* Km     = (const float*)d_in[2];
  const float* E      = (const float*)d_in[3];
  const float* bias   = (const float*)d_in[4];
  const float* Estu   = (const float*)d_in[5];
  const float* phi    = (const float*)d_in[6];
  const float* sigma  = (const float*)d_in[7];
  const float* phistu = (const float*)d_in[8];
  const float* W      = (const float*)d_in[9];
  float* out = (float*)d_out;

  char* ws = (char*)d_ws;
  size_t off = 0;
  auto alloc = [&](size_t bytes) -> void* {
    void* p = ws + off;
    off += (bytes + 255) & ~(size_t)255;
    return p;
  };
  // ---- zero region (one memset): upert, G, XQ, UR, Bbuf[4] = 10 MB ----
  float* upert = (float*)alloc((size_t)512 * 512 * 4);     // 1 MB
  float* G     = (float*)alloc((size_t)512 * 1024 * 4);    // 2 MB
  float* XQ    = (float*)alloc((size_t)512 * 1024 * 4);    // 2 MB
  float* UR    = (float*)alloc((size_t)512 * 512 * 4);     // 1 MB
  float* Bbuf  = (float*)alloc((size_t)4 * 512 * 512 * 4); // 4 MB (one per sweep)
  // ---- rest ----
  float* X     = (float*)alloc((size_t)512 * 1024 * 4);    // 2 MB
  float* Psum  = (float*)alloc((size_t)16 * 1024 * 4);     // 64 KB
  float* Pbuf  = (float*)alloc((size_t)512 * 512 * 4);     // 1 MB
  float* Ufin  = (float*)alloc((size_t)512 * 512 * 4);     // 1 MB
  float* Tot2  = (float*)alloc((size_t)16 * 512 * 4);      // 32 KB
  unsigned short* Ubf0 = (unsigned short*)alloc((size_t)512 * 512 * 2);    // 0.5 MB
  unsigned short* Ubf1 = (unsigned short*)alloc((size_t)512 * 512 * 2);    // 0.5 MB
  unsigned short* Cb   = (unsigned short*)alloc((size_t)512 * 10240 * 2);  // 10 MB
  unsigned short* WWb  = (unsigned short*)alloc((size_t)512 * 5120 * 2);   // 5 MB
  unsigned short* Escb = (unsigned short*)alloc((size_t)512 * 5120 * 2);   // 5 MB
  unsigned short* Et2  = (unsigned short*)alloc((size_t)1024 * 10240 * 2); // 20 MB

  hipMemsetAsync(upert, 0, (size_t)10485760, stream);  // zero region

  ww_kernel<<<dim3(4, 512), 256, 0, stream>>>(W, phi, WWb);
  esc_kernel<<<dim3(4, 512), 256, 0, stream>>>(E, sigma, Escb);
  transpose_conv_kernel<<<dim3(320, 32), 256, 0, stream>>>(Estu, Et2);

  // u_pert_raw(512x512) = WW * Esc^T   [split-K 32, k-fast]
  gemm_bt<false, false><<<dim3(32, 4, 4), 256, 0, stream>>>(WWb, Escb, upert, 5120, 512, 160, 1);
  // Cb(512x10240 bf16) = K(512x1024) * Estu(10240x1024)^T  [direct bf16 store]
  gemm_bt<true, true><<<dim3(1, 80, 4), 256, 0, stream>>>(Km, Estu, (float*)Cb, 1024, 10240, 1024, 3);

  padd_kernel<<<dim3(1024), 256, 0, stream>>>(upert, bias, Pbuf, Ubf0);

  // ---- Jacobi solve of U = P - L(U), 4 sweeps; scan AFTER the GEMM ----
  for (int k = 0; k < 4; ++k) {
    const unsigned short* Asrc = (k & 1) ? Ubf1 : Ubf0;
    unsigned short* Adst = (k & 1) ? Ubf0 : Ubf1;
    float* Bk = Bbuf + (size_t)k * 512 * 512;
    // B[t,c'] += phi[t,f] * (U * C_f^T)   [f-batched, 640 blocks]
    gemm_fbat<2><<<dim3(40, 4, 4), 256, 0, stream>>>(Asrc, Cb, Bk, 512, phistu);
    bsum_kernel<<<dim3(2, 16), 256, 0, stream>>>(Bk, Tot2);
    bscan_kernel<<<dim3(2, 16), 256, 0, stream>>>(Bk, Tot2, Pbuf, Adst, Ufin, (k == 3) ? 1 : 0);
  }
  const unsigned short* Ubf_final = Ubf0;  // k=3 wrote Ubf0
  const float* U = Ufin;

  // G[t,n] += phi[t,f] * (U * E_stu[f])   [f-batched, 1280 blocks]
  gemm_fbat<2><<<dim3(40, 8, 4), 256, 0, stream>>>(Ubf_final, Et2, G, 1024, phistu);

  scan1_kernel<<<dim3(4, 16), 256, 0, stream>>>(G, Psum);
  scan2_kernel<<<dim3(4), 256, 0, stream>>>(Psum);
  scan3_kernel<<<dim3(4, 16), 256, 0, stream>>>(G, Psum, X);

  // XQ = X * Q^T   [split-K 16, k-fast]
  gemm_bt<true, true><<<dim3(16, 8, 4), 256, 0, stream>>>(X, Q, XQ, 1024, 1024, 64, 1);
  // UR = U * R^T   [split-K 8, k-fast]
  gemm_bt<true, true><<<dim3(8, 4, 4), 256, 0, stream>>>(U, R, UR, 512, 512, 64, 1);

  loss_kernel<<<dim3(512), 256, 0, stream>>>(XQ, X, UR, U, out);
  (void)in_sizes; (void)n_in; (void)out_size; (void)ws_size;
}